// Round 7
// baseline (3240.747 us; speedup 1.0000x reference)
//
#include <hip/hip_runtime.h>
#include <hip/hip_fp16.h>

// Unidir_LSTM: h_t = sig(o)*tanh(sig(i)*tanh(g)); f-gate dead (cell carry always 0).
// R12 — DIAGNOSTIC DECOMPOSITION ROUND. Five handoff protocols (R5/R7/R9/R10/R11)
//   all land at 4.5-5.2us/step (+-3%): the step time is insensitive to signal
//   mechanics. Two surviving theories disagree 10x on the same quantity:
//     H-latency: intra-block ~0.3-0.5us, rest = cross-block wait (all fixes null);
//     H-intra:   intra-block itself ~3.5-4.5us (DVFS downclock at 12% occupancy?
//                MFMA/drain stalls?) and the handoff hides under it.
//   This launch enqueues THREE recur dispatches; rocprof reports each separately:
//     recur_t<0>: bit-identical R11 kernel -> writes the real `out` (correctness
//                 anchor, expect ~1150-1190us);
//     recur_t<1>: poll compiled out, free-runs on scratch hbuf2/cnt2/out2 (release
//                 machinery kept). Cannot hang (no spin), cannot touch `out`.
//     recur_t<2>: poll AND release compiled out = pure intra-block skeleton.
//   Decomposition: V2 = intra floor; V1-V2 = release cost; V0-V1 = wait cost.
//   Committed decision rule: V2 in 250-450us => H-latency, next round shortens the
//   chain (payload-with-flag, straggler spread). V2 in 900-1100us => H-intra, stop
//   all protocol work, attack clocks/occupancy/MFMA scheduling.
//   Total dur_us this round ~2.5-3.5ms (sum of 3 dispatches) — accepted cost.

typedef __fp16 f16x8 __attribute__((ext_vector_type(8)));
typedef __fp16 f16x4 __attribute__((ext_vector_type(4)));
typedef float  f32x4 __attribute__((ext_vector_type(4)));

#define MFMA16(a, b, c) __builtin_amdgcn_mfma_f32_16x16x32_f16(a, b, c, 0, 0, 0)

__device__ __forceinline__ float sigmoid_f(float x) {
  return 1.f / (1.f + __expf(-x));
}
__device__ __forceinline__ float tanh_f(float x) {
  x = fminf(fmaxf(x, -15.f), 15.f);
  float e = __expf(2.f * x);
  return (e - 1.f) / (e + 1.f);
}

static constexpr int SS = 256;

// ---------------- prep: pack W_ih/W_hh rows {i,g,o} to fp16, bias3 = b_ih+b_hh ----
__global__ void prep_kernel(const float* __restrict__ W_ih, const float* __restrict__ W_hh,
                            const float* __restrict__ b_ih, const float* __restrict__ b_hh,
                            __fp16* __restrict__ Wi3, __fp16* __restrict__ Wh3,
                            float* __restrict__ bias3) {
  int j3 = blockIdx.x;                 // 0..3071 packed row
  int g = j3 >> 10, j = j3 & 1023;
  int orig = (g == 0 ? 0 : (g == 1 ? 2048 : 3072)) + j;  // i,g,o rows of 4H
  int tid = threadIdx.x;
  {
    float4 v = *(const float4*)(W_hh + (size_t)orig * 1024 + tid * 4);
    f16x4 o = {(__fp16)v.x, (__fp16)v.y, (__fp16)v.z, (__fp16)v.w};
    *(f16x4*)(Wh3 + (size_t)j3 * 1024 + tid * 4) = o;
  }
  if (tid < 128) {
    float4 v = *(const float4*)(W_ih + (size_t)orig * 512 + tid * 4);
    f16x4 o = {(__fp16)v.x, (__fp16)v.y, (__fp16)v.z, (__fp16)v.w};
    *(f16x4*)(Wi3 + (size_t)j3 * 512 + tid * 4) = o;
  }
  if (tid == 0) bias3[j3] = b_ih[orig] + b_hh[orig];
}

// ---------------- gather: X[t*128+b][e] = fp16(embed[tok[b][t]][e]) ----------------
__global__ void gather_kernel(const int* __restrict__ tok, const float* __restrict__ emb,
                              __fp16* __restrict__ X) {
  int m = blockIdx.x;                  // 0..32767 = t*128 + b
  int t = m >> 7, b = m & 127;
  int tk = tok[b * SS + t];            // inputs is [B][S]
  int e0 = threadIdx.x * 8;
  const float* src = emb + (size_t)tk * 512 + e0;
  float4 v0 = *(const float4*)src;
  float4 v1 = *(const float4*)(src + 4);
  f16x8 o;
  o[0] = (__fp16)v0.x; o[1] = (__fp16)v0.y; o[2] = (__fp16)v0.z; o[3] = (__fp16)v0.w;
  o[4] = (__fp16)v1.x; o[5] = (__fp16)v1.y; o[6] = (__fp16)v1.z; o[7] = (__fp16)v1.w;
  *(f16x8*)(X + (size_t)m * 512 + e0) = o;
}

// ---------------- recurrence: R11 structure, templated ablation ------------------
// MODE 0: full (R11 hybrid handoff, bit-identical behavior) — writes real out.
// MODE 1: poll removed (free-run); release (vmcnt+barrier+2 fetch_adds) kept.
// MODE 2: poll AND release removed — pure intra-block compute skeleton.
template <int MODE>
__global__ __launch_bounds__(256, 1) void recur_t(const __fp16* __restrict__ Wh3,
                                                  const __fp16* __restrict__ Wi3,
                                                  const __fp16* __restrict__ X,
                                                  const float* __restrict__ bias3,
                                                  __fp16* __restrict__ hbuf,
                                                  int* __restrict__ cnt,
                                                  float* __restrict__ out) {
  const int bid = blockIdx.x;
  const int bg = bid & 7, n = bid >> 3;   // XCD-local batch groups
  const int b0 = bg * 16, j0 = n * 32;
  const int tid = threadIdx.x, wid = tid >> 6, lane = tid & 63;
  const int l15 = lane & 15, quad = lane >> 4;
  const int kq = wid;                     // this wave's K-quarter
  const int ct_e = wid & 1, rh = wid >> 1;  // epilogue ownership: col-tile, row-half

  // parity-double-buffered; stride 20 floats -> 2-way banks (free, m136)
  __shared__ float gbuf[2][4][3][2][16][20];

  // persistent B fragments (col = j0 + ct*16 + l15, k = quarter + kk*32 + quad*8)
  f16x8 wh[3][2][8];
  f16x8 wi[3][2][4];
#pragma unroll
  for (int g = 0; g < 3; ++g)
#pragma unroll
    for (int ct = 0; ct < 2; ++ct) {
      const __fp16* wr = Wh3 + (size_t)(g * 1024 + j0 + ct * 16 + l15) * 1024 + kq * 256 + quad * 8;
#pragma unroll
      for (int kk = 0; kk < 8; ++kk) wh[g][ct][kk] = *(const f16x8*)(wr + kk * 32);
      const __fp16* wr2 = Wi3 + (size_t)(g * 1024 + j0 + ct * 16 + l15) * 512 + kq * 128 + quad * 8;
#pragma unroll
      for (int kk = 0; kk < 4; ++kk) wi[g][ct][kk] = *(const f16x8*)(wr2 + kk * 32);
    }

  float bs[3];
#pragma unroll
  for (int g = 0; g < 3; ++g) bs[g] = bias3[g * 1024 + j0 + ct_e * 16 + l15];

  const __fp16* xrow = X + (size_t)(b0 + l15) * 512 + kq * 128 + quad * 8;
  const __fp16* hrow = hbuf + (size_t)(b0 + l15) * 1024 + kq * 256 + quad * 8;
  // counter layout: [bg][t][8 lines x 64B]; stride per t = 128 ints
  int* cbase = cnt + bg * (SS * 128);
  const int* pollS0 = cbase + kq * 16;         // + t*128 (agent/MALL)
  const int* pollF0 = cbase + 64 + kq * 16;    // + t*128 (workgroup/L2)
  int* flagS0 = cbase + (n >> 3) * 16;         // + (t+1)*128
  int* flagF0 = cbase + 64 + (n >> 3) * 16;    // + (t+1)*128

  for (int t = 0; t < SS; ++t) {
    // (a) X A-frags + X-MFMAs: fully h-independent -> run BEFORE the poll.
    f16x8 xa[4];
    {
      const __fp16* xp = xrow + (size_t)t * 65536;
#pragma unroll
      for (int kk = 0; kk < 4; ++kk) xa[kk] = *(const f16x8*)(xp + kk * 32);
    }
    f32x4 acc[3][2];
#pragma unroll
    for (int g = 0; g < 3; ++g)
#pragma unroll
      for (int ct = 0; ct < 2; ++ct) {
        f32x4 z = {0.f, 0.f, 0.f, 0.f};
        acc[g][ct] = z;
      }
#pragma unroll
    for (int kk = 0; kk < 4; ++kk)
#pragma unroll
      for (int g = 0; g < 3; ++g)
#pragma unroll
        for (int ct = 0; ct < 2; ++ct)
          acc[g][ct] = MFMA16(xa[kk], wi[g][ct][kk], acc[g][ct]);
    // (b) hybrid poll (MODE 0 only): fast nt-load of L2 workgroup counter OR slow
    //     agent load of MALL counter; break on either. (MODE>=1: compiled out.)
    if (MODE == 0 && t > 0) {
      const int* pF = pollF0 + t * 128;
      const int* pS = pollS0 + t * 128;
      for (;;) {
        asm volatile("" ::: "memory");
        int vf = __builtin_nontemporal_load(pF);
        if (vf >= 8) break;
        int vs = __hip_atomic_load(pS, __ATOMIC_RELAXED, __HIP_MEMORY_SCOPE_AGENT);
        if (vs >= 8) break;
        __builtin_amdgcn_s_sleep(1);
      }
      asm volatile("" ::: "memory");
    }
    // (c) h A-frags global->VGPR (XCD-L2 hit), then 48 h-MFMAs
    f16x8 ha[8];
    {
      const __fp16* hp = hrow + (size_t)t * 131072;
#pragma unroll
      for (int kk = 0; kk < 8; ++kk) ha[kk] = *(const f16x8*)(hp + kk * 32);
    }
#pragma unroll
    for (int kk = 0; kk < 8; ++kk)
#pragma unroll
      for (int g = 0; g < 3; ++g)
#pragma unroll
        for (int ct = 0; ct < 2; ++ct)
          acc[g][ct] = MFMA16(ha[kk], wh[g][ct][kk], acc[g][ct]);
    // (d) 4-way K reduction via parity gbuf (single barrier)
    const int tp = t & 1;
#pragma unroll
    for (int g = 0; g < 3; ++g)
#pragma unroll
      for (int ct = 0; ct < 2; ++ct)
#pragma unroll
        for (int r = 0; r < 4; ++r)
          gbuf[tp][kq][g][ct][quad * 4 + r][l15] = acc[g][ct][r];
    __syncthreads();
    float sum[3][2];
#pragma unroll
    for (int g = 0; g < 3; ++g)
#pragma unroll
      for (int rr = 0; rr < 2; ++rr) {
        const int r = rh * 2 + rr;
        sum[g][rr] = gbuf[tp][0][g][ct_e][quad * 4 + r][l15] + gbuf[tp][1][g][ct_e][quad * 4 + r][l15] +
                     gbuf[tp][2][g][ct_e][quad * 4 + r][l15] + gbuf[tp][3][g][ct_e][quad * 4 + r][l15];
      }
    // (e) epilogue: 2 h-values per thread, all 4 waves participate
#pragma unroll
    for (int rr = 0; rr < 2; ++rr) {
      const int r = rh * 2 + rr;
      float gi = sum[0][rr] + bs[0];
      float gg = sum[1][rr] + bs[1];
      float go = sum[2][rr] + bs[2];
      float cv = sigmoid_f(gi) * tanh_f(gg);
      float hN = sigmoid_f(go) * tanh_f(cv);
      const int row = b0 + quad * 4 + r;
      const int col = j0 + ct_e * 16 + l15;
      if (t == SS - 1) out[(size_t)row * 1024 + col] = hN;
      else hbuf[(size_t)(t + 1) * 131072 + (size_t)row * 1024 + col] = (__fp16)hN;
    }
    // (f) release (MODE <= 1): per-wave drain, block barrier, tid0 fires both
    //     flags. (MODE 2: compiled out entirely — pure compute skeleton.)
    if (MODE <= 1 && t < SS - 1) {
      asm volatile("s_waitcnt vmcnt(0)" ::: "memory");
      __syncthreads();
      if (tid == 0) {
        __hip_atomic_fetch_add(flagF0 + (t + 1) * 128, 1,
                               __ATOMIC_RELAXED, __HIP_MEMORY_SCOPE_WORKGROUP);
        __hip_atomic_fetch_add(flagS0 + (t + 1) * 128, 1,
                               __ATOMIC_RELAXED, __HIP_MEMORY_SCOPE_AGENT);
      }
    }
  }
}

extern "C" void kernel_launch(void* const* d_in, const int* in_sizes, int n_in,
                              void* d_out, int out_size, void* d_ws, size_t ws_size,
                              hipStream_t stream) {
  const int*   tok  = (const int*)d_in[0];
  const float* emb  = (const float*)d_in[1];
  const float* W_ih = (const float*)d_in[2];
  const float* W_hh = (const float*)d_in[3];
  const float* b_ih = (const float*)d_in[4];
  const float* b_hh = (const float*)d_in[5];
  float* out = (float*)d_out;
  char* ws = (char*)d_ws;

  // ws layout (bytes), total 179,843,072 (~172 MB; prior sessions used up to 297 MB)
  __fp16* X     = (__fp16*)(ws + 0);              // 33,554,432
  __fp16* Wi3   = (__fp16*)(ws + 33554432);       //  3,145,728
  __fp16* Wh3   = (__fp16*)(ws + 36700160);       //  6,291,456
  float*  bias3 = (float*) (ws + 42991616);       //     12,288
  int*    cnt   = (int*)   (ws + 43003904);       //  1,048,576
  __fp16* hbuf  = (__fp16*)(ws + 44052480);       // 67,108,864
  int*    cnt2  = (int*)   (ws + 111161344);      //  1,048,576 (V1 scratch flags)
  __fp16* hbuf2 = (__fp16*)(ws + 112209920);      // 67,108,864 (V1/V2 scratch h)
  float*  out2  = (float*) (ws + 179318784);      //    524,288 (V1/V2 scratch out)

  (void)hipMemsetAsync(cnt, 0, 1048576, stream);
  (void)hipMemsetAsync(hbuf, 0, 131072 * 2, stream);   // h_0 = 0
  (void)hipMemsetAsync(cnt2, 0, 1048576, stream);
  (void)hipMemsetAsync(hbuf2, 0, 131072 * 2, stream);  // scratch h_0

  prep_kernel<<<3072, 256, 0, stream>>>(W_ih, W_hh, b_ih, b_hh, Wi3, Wh3, bias3);
  gather_kernel<<<32768, 64, 0, stream>>>(tok, emb, X);
  // V0: the real, correct kernel (identical to R11) — writes `out`.
  recur_t<0><<<256, 256, 0, stream>>>(Wh3, Wi3, X, bias3, hbuf, cnt, out);
  // V1: no-poll ablation (free-run on scratch; release kept). Measures V0-V1 = wait.
  recur_t<1><<<256, 256, 0, stream>>>(Wh3, Wi3, X, bias3, hbuf2, cnt2, out2);
  // V2: no-poll no-release = pure intra-block skeleton. V1-V2 = release cost.
  recur_t<2><<<256, 256, 0, stream>>>(Wh3, Wi3, X, bias3, hbuf2, cnt2, out2);
}

// Round 8
// 1234.803 us; speedup vs baseline: 2.6245x; 2.6245x over previous
//
#include <hip/hip_runtime.h>
#include <hip/hip_fp16.h>

// Unidir_LSTM: h_t = sig(o)*tanh(sig(i)*tanh(g)); f-gate dead (cell carry always 0).
// R13: R12 decomposition: V0(full) ~ V1(no poll) ~ V2(no poll/release) ~ 1170us.
//   => handoff costs ~0; the INTRA-BLOCK skeleton is 4.6us/step. Cross-check:
//   72 MFMA x 4.85cy = 349 busy cy/SIMD/step; MfmaUtil 10.5% => step ~3325cy =>
//   effective clock ~725 MHz (VALUBusy agrees ~875). The chip is DVFS-parked low
//   (10% util, 1 wave/SIMD) and at 1 wave/SIMD every latency is fully exposed.
// Fix (stop protocol work per committed rule; attack the intra-block chain):
//   - 512 threads = 8 waves/block: (ct 0-1 col-tile) x (kq 0-3 K-quarter).
//     Per wave: 36 MFMAs (was 72), 12 ds_write (was 24), 1 epilogue val/thread
//     (was 2), weight regs ~144 (was ~288). 2 waves/SIMD => TLP hides latency,
//     util doubles => DPM clock should rise.
//   - X(t+1) register prefetch: the only HBM/L3-latency load leaves the chain.
//   - __launch_bounds__(512,2) caps VGPR at 256 (~235 est). Spill signature:
//     VGPR_Count=256 + WRITE_SIZE jump => drop prefetch / 6 waves next round.
//   - Handoff: single R9-proven agent counter per (bg,t), threshold 32 (free).
// Predict: recur 1170 -> ~550-800us (total ~700-950), MfmaUtil 18-25%, VALUBusy
//   20-28%, Occupancy ~24%, FETCH 86-100MB, WRITE ~68MB, conflicts ~0.

typedef __fp16 f16x8 __attribute__((ext_vector_type(8)));
typedef __fp16 f16x4 __attribute__((ext_vector_type(4)));
typedef float  f32x4 __attribute__((ext_vector_type(4)));

#define MFMA16(a, b, c) __builtin_amdgcn_mfma_f32_16x16x32_f16(a, b, c, 0, 0, 0)

__device__ __forceinline__ float sigmoid_f(float x) {
  return 1.f / (1.f + __expf(-x));
}
__device__ __forceinline__ float tanh_f(float x) {
  x = fminf(fmaxf(x, -15.f), 15.f);
  float e = __expf(2.f * x);
  return (e - 1.f) / (e + 1.f);
}

static constexpr int SS = 256;

// ---------------- prep: pack W_ih/W_hh rows {i,g,o} to fp16, bias3 = b_ih+b_hh ----
__global__ void prep_kernel(const float* __restrict__ W_ih, const float* __restrict__ W_hh,
                            const float* __restrict__ b_ih, const float* __restrict__ b_hh,
                            __fp16* __restrict__ Wi3, __fp16* __restrict__ Wh3,
                            float* __restrict__ bias3) {
  int j3 = blockIdx.x;                 // 0..3071 packed row
  int g = j3 >> 10, j = j3 & 1023;
  int orig = (g == 0 ? 0 : (g == 1 ? 2048 : 3072)) + j;  // i,g,o rows of 4H
  int tid = threadIdx.x;
  {
    float4 v = *(const float4*)(W_hh + (size_t)orig * 1024 + tid * 4);
    f16x4 o = {(__fp16)v.x, (__fp16)v.y, (__fp16)v.z, (__fp16)v.w};
    *(f16x4*)(Wh3 + (size_t)j3 * 1024 + tid * 4) = o;
  }
  if (tid < 128) {
    float4 v = *(const float4*)(W_ih + (size_t)orig * 512 + tid * 4);
    f16x4 o = {(__fp16)v.x, (__fp16)v.y, (__fp16)v.z, (__fp16)v.w};
    *(f16x4*)(Wi3 + (size_t)j3 * 512 + tid * 4) = o;
  }
  if (tid == 0) bias3[j3] = b_ih[orig] + b_hh[orig];
}

// ---------------- gather: X[t*128+b][e] = fp16(embed[tok[b][t]][e]) ----------------
__global__ void gather_kernel(const int* __restrict__ tok, const float* __restrict__ emb,
                              __fp16* __restrict__ X) {
  int m = blockIdx.x;                  // 0..32767 = t*128 + b
  int t = m >> 7, b = m & 127;
  int tk = tok[b * SS + t];            // inputs is [B][S]
  int e0 = threadIdx.x * 8;
  const float* src = emb + (size_t)tk * 512 + e0;
  float4 v0 = *(const float4*)src;
  float4 v1 = *(const float4*)(src + 4);
  f16x8 o;
  o[0] = (__fp16)v0.x; o[1] = (__fp16)v0.y; o[2] = (__fp16)v0.z; o[3] = (__fp16)v0.w;
  o[4] = (__fp16)v1.x; o[5] = (__fp16)v1.y; o[6] = (__fp16)v1.z; o[7] = (__fp16)v1.w;
  *(f16x8*)(X + (size_t)m * 512 + e0) = o;
}

// ---------------- recurrence: 8 waves/block, 2 waves/SIMD, X prefetch ------------
// 256 blocks = (bg 0..7: 16 batch rows, XCD-pinned via bid&7) x (n 0..31: 32
// h-cols). 8 waves = (ct 0..1: 16-col tile) x (kq 0..3: K-quarter). Per step,
// per wave: 12 X-MFMAs on prefetched xa (pre-poll), prefetch xa(t+1), poll the
// single (bg,t) agent counter, 8 h A-frag loads (XCD-L2), 24 h-MFMAs, publish
// 12 partials to parity gbuf, barrier, epilogue 1 h-value/thread (8-wave split:
// ct_e = wid&1, row-quad rq = wid>>1), per-wave vmcnt(0), release barrier, tid0
// agent fetch_add on (bg,t+1). ct-pair waves duplicate X/h loads (L2-absorbed).
__global__ __launch_bounds__(512, 2) void recur_kernel(const __fp16* __restrict__ Wh3,
                                                       const __fp16* __restrict__ Wi3,
                                                       const __fp16* __restrict__ X,
                                                       const float* __restrict__ bias3,
                                                       __fp16* __restrict__ hbuf,
                                                       int* __restrict__ cnt,
                                                       float* __restrict__ out) {
  const int bid = blockIdx.x;
  const int bg = bid & 7, n = bid >> 3;   // XCD-local batch groups
  const int b0 = bg * 16, j0 = n * 32;
  const int tid = threadIdx.x, wid = tid >> 6, lane = tid & 63;
  const int l15 = lane & 15, quad = lane >> 4;
  const int kq = wid >> 1, ct = wid & 1;  // compute ownership: K-quarter, col-tile
  const int ct_e = wid & 1, rq = wid >> 1;  // epilogue ownership: col-tile, row-quad
  const int lr = lane >> 4;               // epilogue row within quad (0..3)

  // parity-double-buffered; stride 20 floats -> <=2-way banks (free, m136)
  __shared__ float gbuf[2][4][3][2][16][20];

  // persistent B fragments (col = j0 + ct*16 + l15, k = kq*quarter + kk*32 + quad*8)
  f16x8 wh[3][8];
  f16x8 wi[3][4];
#pragma unroll
  for (int g = 0; g < 3; ++g) {
    const __fp16* wr = Wh3 + (size_t)(g * 1024 + j0 + ct * 16 + l15) * 1024 + kq * 256 + quad * 8;
#pragma unroll
    for (int kk = 0; kk < 8; ++kk) wh[g][kk] = *(const f16x8*)(wr + kk * 32);
    const __fp16* wr2 = Wi3 + (size_t)(g * 1024 + j0 + ct * 16 + l15) * 512 + kq * 128 + quad * 8;
#pragma unroll
    for (int kk = 0; kk < 4; ++kk) wi[g][kk] = *(const f16x8*)(wr2 + kk * 32);
  }

  float bs[3];
#pragma unroll
  for (int g = 0; g < 3; ++g) bs[g] = bias3[g * 1024 + j0 + ct_e * 16 + l15];

  const __fp16* xrow = X + (size_t)(b0 + l15) * 512 + kq * 128 + quad * 8;
  const __fp16* hrow = hbuf + (size_t)(b0 + l15) * 1024 + kq * 256 + quad * 8;
  int* cbase = cnt + bg * (SS * 16);      // one 64B line per (bg, t)

  // preload X A-frags for t=0 (prefetch pipeline prologue)
  f16x8 xa[4];
#pragma unroll
  for (int kk = 0; kk < 4; ++kk) xa[kk] = *(const f16x8*)(xrow + kk * 32);

  for (int t = 0; t < SS; ++t) {
    // (a) X-MFMAs on the prefetched frags — h-independent, before the poll
    f32x4 acc[3];
#pragma unroll
    for (int g = 0; g < 3; ++g) {
      f32x4 z = {0.f, 0.f, 0.f, 0.f};
      acc[g] = z;
    }
#pragma unroll
    for (int kk = 0; kk < 4; ++kk)
#pragma unroll
      for (int g = 0; g < 3; ++g)
        acc[g] = MFMA16(xa[kk], wi[g][kk], acc[g]);
    // (a2) prefetch X A-frags for t+1 (overwrites xa after its last use above);
    //      latency retires under the poll + h-phase of this step.
    {
      const int tn = (t + 1 < SS) ? t + 1 : t;
      const __fp16* xp = xrow + (size_t)tn * 65536;
#pragma unroll
      for (int kk = 0; kk < 4; ++kk) xa[kk] = *(const f16x8*)(xp + kk * 32);
    }
    // (b) wait for the 32 producer blocks of our batch group (R9-proven scheme:
    //     agent-scope relaxed load of one aggregated counter; measured cost ~0)
    if (t > 0) {
      const int* pollp = cbase + t * 16;
      for (;;) {
        int v = __hip_atomic_load(pollp, __ATOMIC_RELAXED, __HIP_MEMORY_SCOPE_AGENT);
        if (v >= 32) break;
        __builtin_amdgcn_s_sleep(1);
      }
      asm volatile("" ::: "memory");
    }
    // (c) h A-frags global->VGPR (XCD-L2 hit), then 24 h-MFMAs
    f16x8 ha[8];
    {
      const __fp16* hp = hrow + (size_t)t * 131072;
#pragma unroll
      for (int kk = 0; kk < 8; ++kk) ha[kk] = *(const f16x8*)(hp + kk * 32);
    }
#pragma unroll
    for (int kk = 0; kk < 8; ++kk)
#pragma unroll
      for (int g = 0; g < 3; ++g)
        acc[g] = MFMA16(ha[kk], wh[g][kk], acc[g]);
    // (d) publish partials to parity gbuf (12 ds_write_b32/thread)
    const int tp = t & 1;
#pragma unroll
    for (int g = 0; g < 3; ++g)
#pragma unroll
      for (int r = 0; r < 4; ++r)
        gbuf[tp][kq][g][ct][quad * 4 + r][l15] = acc[g][r];
    __syncthreads();
    // (e) reduce + epilogue: ONE h-value per thread (512 threads = 16x32 outputs)
    {
      const int row_i = rq * 4 + lr;
      float s[3];
#pragma unroll
      for (int g = 0; g < 3; ++g)
        s[g] = gbuf[tp][0][g][ct_e][row_i][l15] + gbuf[tp][1][g][ct_e][row_i][l15] +
               gbuf[tp][2][g][ct_e][row_i][l15] + gbuf[tp][3][g][ct_e][row_i][l15];
      float gi = s[0] + bs[0];
      float gg = s[1] + bs[1];
      float go = s[2] + bs[2];
      float cv = sigmoid_f(gi) * tanh_f(gg);
      float hN = sigmoid_f(go) * tanh_f(cv);
      const int row = b0 + row_i;
      const int col = j0 + ct_e * 16 + l15;
      if (t == SS - 1) out[(size_t)row * 1024 + col] = hN;
      else hbuf[(size_t)(t + 1) * 131072 + (size_t)row * 1024 + col] = (__fp16)hN;
    }
    // (f) release: per-wave drain into the XCD L2, block barrier, then ONE agent
    //     fetch_add (MALL, device-visible, hang-proof; measured cost ~0).
    if (t < SS - 1) {
      asm volatile("s_waitcnt vmcnt(0)" ::: "memory");
      __syncthreads();
      if (tid == 0)
        __hip_atomic_fetch_add(cbase + (t + 1) * 16, 1,
                               __ATOMIC_RELAXED, __HIP_MEMORY_SCOPE_AGENT);
    }
  }
}

extern "C" void kernel_launch(void* const* d_in, const int* in_sizes, int n_in,
                              void* d_out, int out_size, void* d_ws, size_t ws_size,
                              hipStream_t stream) {
  const int*   tok  = (const int*)d_in[0];
  const float* emb  = (const float*)d_in[1];
  const float* W_ih = (const float*)d_in[2];
  const float* W_hh = (const float*)d_in[3];
  const float* b_ih = (const float*)d_in[4];
  const float* b_hh = (const float*)d_in[5];
  float* out = (float*)d_out;
  char* ws = (char*)d_ws;

  // ws layout (bytes), total 110,243,840 (~105 MB)
  __fp16* X     = (__fp16*)(ws + 0);              // 33,554,432
  __fp16* Wi3   = (__fp16*)(ws + 33554432);       //  3,145,728
  __fp16* Wh3   = (__fp16*)(ws + 36700160);       //  6,291,456
  float*  bias3 = (float*) (ws + 42991616);       //     12,288
  int*    cnt   = (int*)   (ws + 43003904);       //    131,072 (8 grp x 256 t, 64B lines)
  __fp16* hbuf  = (__fp16*)(ws + 43134976);       // 67,108,864 (256 step buffers)

  (void)hipMemsetAsync(cnt, 0, 131072, stream);
  (void)hipMemsetAsync(hbuf, 0, 131072 * 2, stream);  // h_0 = 0

  prep_kernel<<<3072, 256, 0, stream>>>(W_ih, W_hh, b_ih, b_hh, Wi3, Wh3, bias3);
  gather_kernel<<<32768, 64, 0, stream>>>(tok, emb, X);
  recur_kernel<<<256, 512, 0, stream>>>(Wh3, Wi3, X, bias3, hbuf, cnt, out);
}